// Round 9
// baseline (504.092 us; speedup 1.0000x reference)
//
#include <hip/hip_runtime.h>
#include <math.h>

#define NRES 4096
#define SS   128
#define A0C  5
#define ATOT 16
#define LD   256
#define PD   64
#define HD   128

typedef __attribute__((ext_vector_type(8))) short bf16x8;
typedef __attribute__((ext_vector_type(4))) float f32x4;

__device__ __forceinline__ unsigned short f2bf(float x){
    unsigned int u = __builtin_bit_cast(unsigned int, x);
    unsigned int r = u + 0x7FFFu + ((u >> 16) & 1u);   // RNE to bf16
    return (unsigned short)(r >> 16);
}
__device__ __forceinline__ float gelu_f(float x){
    // x/(1+e^{-2t}), 2t = 1.59576912*(x + 0.044715 x^3)  == tanh-gelu exactly
    return x / (1.0f + __expf(-1.59576912f * x * (1.0f + 0.044715f * x * x)));
}
__device__ __forceinline__ f32x4 MFMA(bf16x8 a, bf16x8 b, f32x4 c){
    return __builtin_amdgcn_mfma_f32_16x16x32_bf16(a, b, c, 0, 0, 0);
}

// ---------------- prep: transpose+convert weights to bf16 in d_ws ----------------
// layout (ushort elements)  [identical to r5/r8]:
//   [0)      wsD   [64 n][256 k]   (w_dist^T)
//   [16384)  wsDir [64 n][64 k]    (w_dir^T, k>=48 zero)
//   [20480)  wsM1  [128 n][64 k]   (w_mlp1^T)
//   [28672)  wsM2  [64 n][128 k]   (w_mlp2^T)   total 36864 ushort = 73728 B
__global__ void smol_prep(const float* __restrict__ wdist, const float* __restrict__ wdir,
                          const float* __restrict__ wm1,  const float* __restrict__ wm2,
                          unsigned short* __restrict__ ws)
{
    int i = blockIdx.x * 256 + threadIdx.x;
    if (i < 16384){
        int nn = i >> 8, k = i & 255;
        ws[i] = f2bf(wdist[k*64 + nn]);
    } else if (i < 20480){
        int j = i - 16384; int nn = j >> 6, k = j & 63;
        ws[i] = (k < 48) ? f2bf(wdir[k*64 + nn]) : (unsigned short)0;
    } else if (i < 28672){
        int j = i - 20480; int nn = j >> 6, k = j & 63;
        ws[i] = f2bf(wm1[k*128 + nn]);
    } else if (i < 36864){
        int j = i - 28672; int nn = j >> 7, k = j & 127;
        ws[i] = f2bf(wm2[k*64 + nn]);
    }
}

// ---------------- main fused kernel ----------------
struct __align__(16) SMem {
    float  dist[64*17];             // [s][a], pad 17
    float  invd[64*17];
    unsigned short pairT[64*72];    // bf16 [s][k<=64], stride 72 (144B = 4 mod 32 words)
    unsigned short hidT[64*136];    // bf16 [s][k<=128], stride 136 (272B = 4 mod 32 words)
    float  smolpos[64*3];
    float  loc[LD];
    float  posall3[ATOT*3];
    float  pl[33];
    float  rot[9];
    float  ca3[3];
    float  wtypef[7*PD];
    float  basev[PD];
    float  gatevv[PD];
    float  lnsc[PD], lnof[PD];
    float  b1v[HD], b2v[PD];
    int    typef[SS];
    float  maskf[SS];
    float  red[4*PD];
    float  fin[PD];
    float  cnt;
};

// Branchless dir-fragment element (r9): clamped index + scalar selects.
// Replaces the divergent `if (k0<48){av[0..7]=..}else{..}` aggregate merge —
// the last surviving construct introduced at r3 (when WRITE_SIZE jumped
// 4MB -> 650MB) that can force an alloca.
__device__ __forceinline__ unsigned short dirbf(const SMem& sm, int sl, int k){
    int kc = (k < 48) ? k : 47;
    int a = (kc * 21846) >> 16;     // kc/3
    int c = kc - 3*a;
    float e = (sm.smolpos[sl*3+c] - sm.posall3[a*3+c]) * sm.invd[sl*17+a];
    return (k < 48) ? f2bf(e) : (unsigned short)0;
}

__global__ __launch_bounds__(256, 3)
void smol_fused(const float* __restrict__ g_local,
                const float* __restrict__ g_pos,
                const int*   __restrict__ g_type,
                const float* __restrict__ g_spos,
                const int*   __restrict__ g_mask,
                const float* __restrict__ w_points,
                const float* __restrict__ w_local,
                const float* __restrict__ w_type,
                const float* __restrict__ ln_scale,
                const float* __restrict__ ln_offset,
                const float* __restrict__ b_mlp1,
                const float* __restrict__ b_mlp2,
                const float* __restrict__ w_gate,
                const float* __restrict__ w_out,
                const unsigned short* __restrict__ ws,
                float* __restrict__ g_out)
{
    __shared__ SMem sm;
    const int n    = blockIdx.x;
    const int tid  = threadIdx.x;
    const int wv   = tid >> 6;        // wave 0..3 : owns rows 16wv..16wv+15
    const int lane = tid & 63;
    const int cB   = lane & 15;       // A-row / B-col selector
    const int g    = lane >> 4;       // k-subgroup 0..3
    const int m0   = wv * 16;
    const int sl   = m0 + cB;         // this lane's A row (chunk-local s)

    const unsigned short* wsD   = ws;
    const unsigned short* wsDir = ws + 16384;
    const unsigned short* wsM1  = ws + 20480;
    const unsigned short* wsM2  = ws + 28672;

    // ---------- stage per-n data + small weights ----------
    sm.loc[tid] = g_local[n*LD + tid];
    sm.wtypef[tid] = w_type[tid];
    if (tid < 7*PD - 256) sm.wtypef[256 + tid] = w_type[256 + tid];
    if (tid < PD){ sm.lnsc[tid] = ln_scale[tid]; sm.lnof[tid] = ln_offset[tid]; sm.b2v[tid] = b_mlp2[tid]; }
    if (tid < HD) sm.b1v[tid] = b_mlp1[tid];
    if (tid < SS){ sm.typef[tid] = g_type[n*SS + tid];
                   sm.maskf[tid] = (g_mask[n*SS + tid] != 0) ? 1.0f : 0.0f; }
    if (tid >= 128 && tid < 128 + A0C*3) sm.posall3[tid-128] = g_pos[n*A0C*3 + (tid-128)];
    __syncthreads();

    // ---------- per-n precompute ----------
    if (tid < 33){
        float a = 0.f;
        for (int i = 0; i < LD; ++i) a += sm.loc[i] * w_points[i*33 + tid];
        sm.pl[tid] = a;
    } else if (tid >= 64 && tid < 128){
        int p = tid - 64; float a = 0.f;
        for (int i = 0; i < LD; ++i) a += sm.loc[i] * w_local[i*PD + p];
        sm.basev[p] = a;
    } else if (tid >= 128 && tid < 192){
        int p = tid - 128; float a = 0.f;
        for (int i = 0; i < LD; ++i) a += sm.loc[i] * w_gate[i*PD + p];
        sm.gatevv[p] = gelu_f(a);
    } else if (tid == 255){
        float nx=sm.posall3[0], ny=sm.posall3[1], nz=sm.posall3[2];
        float cax=sm.posall3[3], cay=sm.posall3[4], caz=sm.posall3[5];
        float cx=sm.posall3[6], cy=sm.posall3[7], cz=sm.posall3[8];
        float v1x=cx-cax, v1y=cy-cay, v1z=cz-caz;
        float r = 1.0f/sqrtf(v1x*v1x + v1y*v1y + v1z*v1z + 1e-6f);
        float e1x=v1x*r, e1y=v1y*r, e1z=v1z*r;
        float v2x=nx-cax, v2y=ny-cay, v2z=nz-caz;
        float dp = e1x*v2x + e1y*v2y + e1z*v2z;
        float u2x=v2x-e1x*dp, u2y=v2y-e1y*dp, u2z=v2z-e1z*dp;
        r = 1.0f/sqrtf(u2x*u2x + u2y*u2y + u2z*u2z + 1e-6f);
        float e2x=u2x*r, e2y=u2y*r, e2z=u2z*r;
        float e3x=e1y*e2z-e1z*e2y, e3y=e1z*e2x-e1x*e2z, e3z=e1x*e2y-e1y*e2x;
        sm.rot[0]=e1x; sm.rot[1]=e2x; sm.rot[2]=e3x;
        sm.rot[3]=e1y; sm.rot[4]=e2y; sm.rot[5]=e3y;
        sm.rot[6]=e1z; sm.rot[7]=e2z; sm.rot[8]=e3z;
        sm.ca3[0]=cax; sm.ca3[1]=cay; sm.ca3[2]=caz;
    } else if (tid == 254){
        float c = 0.f;
        for (int s = 0; s < SS; ++s) c += sm.maskf[s];
        sm.cnt = c;
    }
    __syncthreads();
    if (tid < 33){
        int k = tid / 3, i2 = tid - k*3;
        sm.posall3[(A0C + k)*3 + i2] =
            sm.rot[i2*3+0]*sm.pl[k*3+0] + sm.rot[i2*3+1]*sm.pl[k*3+1] +
            sm.rot[i2*3+2]*sm.pl[k*3+2] + sm.ca3[i2];
    }
    __syncthreads();

    float pooled0 = 0.f, pooled1 = 0.f, pooled2 = 0.f, pooled3 = 0.f;

    // ====== chunk loop. r9: phase-sync barriers (uniform flow, all LDS deps
    // wave-local -> correctness-neutral) so the 4 waves stream the same weight
    // region together: per-phase working set fits the 32KB L1. ======
    for (int ch = 0; ch < 2; ++ch){
        const int sbase = ch * 64;

        // smolpos rows for this wave
        if (lane < 48){
            int sr = m0 + lane/3, c3 = lane - 3*(lane/3);
            sm.smolpos[sr*3 + c3] = g_spos[(n*SS + sbase + sr)*3 + c3];
        }
        // dist + invd for this wave's 16 rows (lane: row cB, atoms g*4..+4)
        {
            float px = sm.smolpos[sl*3+0], py = sm.smolpos[sl*3+1], pz = sm.smolpos[sl*3+2];
            #pragma unroll
            for (int aa = 0; aa < 4; ++aa){
                int a = g*4 + aa;
                float rx = px - sm.posall3[a*3+0];
                float ry = py - sm.posall3[a*3+1];
                float rz = pz - sm.posall3[a*3+2];
                float d  = sqrtf(rx*rx + ry*ry + rz*rz + 1e-6f);
                sm.dist[sl*17 + a] = d;
                sm.invd[sl*17 + a] = 1.0f / d;
            }
        }

        __syncthreads();   // phase-align: wsD streaming

        // ---- pair GEMM: dist-RBF (K=256) ----
        f32x4 accP0 = {0.f,0.f,0.f,0.f}, accP1 = accP0, accP2 = accP0, accP3 = accP0;

        #pragma unroll 2
        for (int kk = 0; kk < 8; ++kk){
            float d  = sm.dist[sl*17 + 2*kk + (g>>1)];
            float dd = d * 1.33333333f;
            float b0f = (float)((g&1) * 8);
            float z0 = dd - 1.06666667f*(b0f + 0.f);
            float z1 = dd - 1.06666667f*(b0f + 1.f);
            float z2 = dd - 1.06666667f*(b0f + 2.f);
            float z3 = dd - 1.06666667f*(b0f + 3.f);
            float z4 = dd - 1.06666667f*(b0f + 4.f);
            float z5 = dd - 1.06666667f*(b0f + 5.f);
            float z6 = dd - 1.06666667f*(b0f + 6.f);
            float z7 = dd - 1.06666667f*(b0f + 7.f);
            bf16x8 av;
            av[0] = (short)f2bf(__expf(-z0*z0));
            av[1] = (short)f2bf(__expf(-z1*z1));
            av[2] = (short)f2bf(__expf(-z2*z2));
            av[3] = (short)f2bf(__expf(-z3*z3));
            av[4] = (short)f2bf(__expf(-z4*z4));
            av[5] = (short)f2bf(__expf(-z5*z5));
            av[6] = (short)f2bf(__expf(-z6*z6));
            av[7] = (short)f2bf(__expf(-z7*z7));

            const unsigned short* bb = wsD + cB*256 + kk*32 + g*8;
            accP0 = MFMA(av, *(const bf16x8*)(bb),          accP0);
            accP1 = MFMA(av, *(const bf16x8*)(bb + 16*256), accP1);
            accP2 = MFMA(av, *(const bf16x8*)(bb + 32*256), accP2);
            accP3 = MFMA(av, *(const bf16x8*)(bb + 48*256), accP3);
        }

        __syncthreads();   // phase-align: wsDir streaming

        // ---- + directions @ w_dir (K=48 pad 64), branchless frags ----
        #pragma unroll
        for (int kk = 0; kk < 2; ++kk){
            int k0 = kk*32 + g*8;
            bf16x8 av;
            av[0] = (short)dirbf(sm, sl, k0+0);
            av[1] = (short)dirbf(sm, sl, k0+1);
            av[2] = (short)dirbf(sm, sl, k0+2);
            av[3] = (short)dirbf(sm, sl, k0+3);
            av[4] = (short)dirbf(sm, sl, k0+4);
            av[5] = (short)dirbf(sm, sl, k0+5);
            av[6] = (short)dirbf(sm, sl, k0+6);
            av[7] = (short)dirbf(sm, sl, k0+7);
            const unsigned short* bb = wsDir + cB*64 + k0;
            accP0 = MFMA(av, *(const bf16x8*)(bb),         accP0);
            accP1 = MFMA(av, *(const bf16x8*)(bb + 16*64), accP1);
            accP2 = MFMA(av, *(const bf16x8*)(bb + 32*64), accP2);
            accP3 = MFMA(av, *(const bf16x8*)(bb + 48*64), accP3);
        }

        // ---- epilogue: + base + wtype, LayerNorm, direct b16 stores ----
        #pragma unroll
        for (int r = 0; r < 4; ++r){
            int slr = m0 + g*4 + r;
            int ty  = sm.typef[sbase + slr];
            float v0 = accP0[r] + sm.basev[cB +  0] + sm.wtypef[ty*PD + cB +  0];
            float v1 = accP1[r] + sm.basev[cB + 16] + sm.wtypef[ty*PD + cB + 16];
            float v2 = accP2[r] + sm.basev[cB + 32] + sm.wtypef[ty*PD + cB + 32];
            float v3 = accP3[r] + sm.basev[cB + 48] + sm.wtypef[ty*PD + cB + 48];
            float ssum = v0+v1+v2+v3;
            ssum += __shfl_xor(ssum,1); ssum += __shfl_xor(ssum,2);
            ssum += __shfl_xor(ssum,4); ssum += __shfl_xor(ssum,8);
            float mu = ssum * (1.0f/64.0f);
            float d0=v0-mu, d1=v1-mu, d2=v2-mu, d3=v3-mu;
            float sq = d0*d0+d1*d1+d2*d2+d3*d3;
            sq += __shfl_xor(sq,1); sq += __shfl_xor(sq,2);
            sq += __shfl_xor(sq,4); sq += __shfl_xor(sq,8);
            float inv = 1.0f / sqrtf(sq*(1.0f/64.0f) + 1e-5f);
            unsigned short* pr = &sm.pairT[slr*72];
            pr[cB +  0] = f2bf(d0*inv*sm.lnsc[cB +  0] + sm.lnof[cB +  0]);
            pr[cB + 16] = f2bf(d1*inv*sm.lnsc[cB + 16] + sm.lnof[cB + 16]);
            pr[cB + 32] = f2bf(d2*inv*sm.lnsc[cB + 32] + sm.lnof[cB + 32]);
            pr[cB + 48] = f2bf(d3*inv*sm.lnsc[cB + 48] + sm.lnof[cB + 48]);
        }

        __syncthreads();   // phase-align: wsM1 streaming

        // ---- MLP1 (K=64, N=128) ----
        f32x4 accH0 = {0.f,0.f,0.f,0.f}, accH1 = accH0, accH2 = accH0, accH3 = accH0,
              accH4 = accH0, accH5 = accH0, accH6 = accH0, accH7 = accH0;
        #pragma unroll
        for (int kk = 0; kk < 2; ++kk){
            bf16x8 a1 = *(const bf16x8*)&sm.pairT[(m0+cB)*72 + kk*32 + g*8];
            const unsigned short* bb = wsM1 + cB*64 + kk*32 + g*8;
            accH0 = MFMA(a1, *(const bf16x8*)(bb + 0*16*64), accH0);
            accH1 = MFMA(a1, *(const bf16x8*)(bb + 1*16*64), accH1);
            accH2 = MFMA(a1, *(const bf16x8*)(bb + 2*16*64), accH2);
            accH3 = MFMA(a1, *(const bf16x8*)(bb + 3*16*64), accH3);
            accH4 = MFMA(a1, *(const bf16x8*)(bb + 4*16*64), accH4);
            accH5 = MFMA(a1, *(const bf16x8*)(bb + 5*16*64), accH5);
            accH6 = MFMA(a1, *(const bf16x8*)(bb + 6*16*64), accH6);
            accH7 = MFMA(a1, *(const bf16x8*)(bb + 7*16*64), accH7);
        }
        // gelu + direct b16 stores
        #pragma unroll
        for (int r = 0; r < 4; ++r){
            int slr = m0 + g*4 + r;
            unsigned short* hr = &sm.hidT[slr*136];
            hr[cB + 0*16] = f2bf(gelu_f(accH0[r] + sm.b1v[cB + 0*16]));
            hr[cB + 1*16] = f2bf(gelu_f(accH1[r] + sm.b1v[cB + 1*16]));
            hr[cB + 2*16] = f2bf(gelu_f(accH2[r] + sm.b1v[cB + 2*16]));
            hr[cB + 3*16] = f2bf(gelu_f(accH3[r] + sm.b1v[cB + 3*16]));
            hr[cB + 4*16] = f2bf(gelu_f(accH4[r] + sm.b1v[cB + 4*16]));
            hr[cB + 5*16] = f2bf(gelu_f(accH5[r] + sm.b1v[cB + 5*16]));
            hr[cB + 6*16] = f2bf(gelu_f(accH6[r] + sm.b1v[cB + 6*16]));
            hr[cB + 7*16] = f2bf(gelu_f(accH7[r] + sm.b1v[cB + 7*16]));
        }

        __syncthreads();   // phase-align: wsM2 streaming

        // ---- MLP2 (K=128, N=64) + masked pooling ----
        f32x4 accO0 = {0.f,0.f,0.f,0.f}, accO1 = accO0, accO2 = accO0, accO3 = accO0;
        #pragma unroll
        for (int kk = 0; kk < 4; ++kk){
            bf16x8 a2 = *(const bf16x8*)&sm.hidT[(m0+cB)*136 + kk*32 + g*8];
            const unsigned short* bb = wsM2 + cB*128 + kk*32 + g*8;
            accO0 = MFMA(a2, *(const bf16x8*)(bb + 0*16*128), accO0);
            accO1 = MFMA(a2, *(const bf16x8*)(bb + 1*16*128), accO1);
            accO2 = MFMA(a2, *(const bf16x8*)(bb + 2*16*128), accO2);
            accO3 = MFMA(a2, *(const bf16x8*)(bb + 3*16*128), accO3);
        }
        #pragma unroll
        for (int r = 0; r < 4; ++r){
            float m = sm.maskf[sbase + m0 + g*4 + r];
            pooled0 += m * accO0[r];
            pooled1 += m * accO1[r];
            pooled2 += m * accO2[r];
            pooled3 += m * accO3[r];
        }
    } // chunk loop

    // ---- reduce pooled: across g-groups (same col), then across waves ----
    pooled0 += __shfl_xor(pooled0,16); pooled0 += __shfl_xor(pooled0,32);
    pooled1 += __shfl_xor(pooled1,16); pooled1 += __shfl_xor(pooled1,32);
    pooled2 += __shfl_xor(pooled2,16); pooled2 += __shfl_xor(pooled2,32);
    pooled3 += __shfl_xor(pooled3,16); pooled3 += __shfl_xor(pooled3,32);
    if (g == 0){
        sm.red[wv*PD + cB +  0] = pooled0;
        sm.red[wv*PD + cB + 16] = pooled1;
        sm.red[wv*PD + cB + 32] = pooled2;
        sm.red[wv*PD + cB + 48] = pooled3;
    }
    __syncthreads();
    if (tid < PD){
        float v = sm.red[tid] + sm.red[PD + tid] + sm.red[2*PD + tid] + sm.red[3*PD + tid];
        float mc = fmaxf(sm.cnt, 1.0f);
        v = (v + sm.cnt * sm.b2v[tid]) / mc;        // adds b2 exactly like ref (0 if cnt==0)
        sm.fin[tid] = sm.gatevv[tid] * v;
    }
    __syncthreads();
    {
        float a = 0.f;
        #pragma unroll 4
        for (int p = 0; p < PD; ++p) a += sm.fin[p] * w_out[p*LD + tid];
        g_out[n*LD + tid] = a;
    }
}

extern "C" void kernel_launch(void* const* d_in, const int* in_sizes, int n_in,
                              void* d_out, int out_size, void* d_ws, size_t ws_size,
                              hipStream_t stream)
{
    (void)in_sizes; (void)n_in; (void)out_size; (void)ws_size;
    const float* g_local   = (const float*)d_in[0];
    const float* g_pos     = (const float*)d_in[1];
    const int*   g_type    = (const int*)  d_in[2];
    const float* g_spos    = (const float*)d_in[3];
    const int*   g_mask    = (const int*)  d_in[4];
    const float* w_points  = (const float*)d_in[5];
    const float* w_type    = (const float*)d_in[6];
    const float* w_local   = (const float*)d_in[7];
    const float* w_dir     = (const float*)d_in[8];
    const float* w_dist    = (const float*)d_in[9];
    const float* ln_scale  = (const float*)d_in[10];
    const float* ln_offset = (const float*)d_in[11];
    const float* w_mlp1    = (const float*)d_in[12];
    const float* b_mlp1    = (const float*)d_in[13];
    const float* w_mlp2    = (const float*)d_in[14];
    const float* b_mlp2    = (const float*)d_in[15];
    const float* w_gate    = (const float*)d_in[16];
    const float* w_out     = (const float*)d_in[17];

    unsigned short* ws = (unsigned short*)d_ws;   // needs 73728 B

    smol_prep<<<dim3(144), dim3(256), 0, stream>>>(w_dist, w_dir, w_mlp1, w_mlp2, ws);

    smol_fused<<<dim3(NRES), dim3(256), 0, stream>>>(
        g_local, g_pos, g_type, g_spos, g_mask,
        w_points, w_local, w_type, ln_scale, ln_offset,
        b_mlp1, b_mlp2, w_gate, w_out, ws, (float*)d_out);
}

// Round 11
// 251.901 us; speedup vs baseline: 2.0011x; 2.0011x over previous
//
#include <hip/hip_runtime.h>
#include <math.h>

#define NRES 4096
#define SS   128
#define A0C  5
#define ATOT 16
#define LD   256
#define PD   64
#define HD   128

typedef __attribute__((ext_vector_type(8))) short bf16x8;
typedef __attribute__((ext_vector_type(4))) float f32x4;
typedef __attribute__((ext_vector_type(4))) unsigned int u32x4;

__device__ __forceinline__ unsigned short f2bf(float x){
    unsigned int u = __builtin_bit_cast(unsigned int, x);
    unsigned int r = u + 0x7FFFu + ((u >> 16) & 1u);   // RNE to bf16
    return (unsigned short)(r >> 16);
}
__device__ __forceinline__ float gelu_f(float x){
    // x/(1+e^{-2t}), 2t = 1.59576912*(x + 0.044715 x^3)  == tanh-gelu exactly
    return x / (1.0f + __expf(-1.59576912f * x * (1.0f + 0.044715f * x * x)));
}
__device__ __forceinline__ f32x4 MFMA(bf16x8 a, bf16x8 b, f32x4 c){
    return __builtin_amdgcn_mfma_f32_16x16x32_bf16(a, b, c, 0, 0, 0);
}

// ---------------- prep: transpose+convert weights to bf16 in d_ws ----------------
// layout (ushort elements)  [identical to r5/r8/r9/r10 — 73728 B total]:
//   [0)      wsD   [64 n][256 k]   (w_dist^T)
//   [16384)  wsDir [64 n][64 k]    (w_dir^T, k>=48 zero)
//   [20480)  wsM1  [128 n][64 k]   (w_mlp1^T)
//   [28672)  wsM2  [64 n][128 k]   (w_mlp2^T)
__global__ void smol_prep(const float* __restrict__ wdist, const float* __restrict__ wdir,
                          const float* __restrict__ wm1,  const float* __restrict__ wm2,
                          unsigned short* __restrict__ ws)
{
    int i = blockIdx.x * 256 + threadIdx.x;
    if (i < 16384){
        int nn = i >> 8, k = i & 255;
        ws[i] = f2bf(wdist[k*64 + nn]);
    } else if (i < 20480){
        int j = i - 16384; int nn = j >> 6, k = j & 63;
        ws[i] = (k < 48) ? f2bf(wdir[k*64 + nn]) : (unsigned short)0;
    } else if (i < 28672){
        int j = i - 20480; int nn = j >> 6, k = j & 63;
        ws[i] = f2bf(wm1[k*128 + nn]);
    } else if (i < 36864){
        int j = i - 28672; int nn = j >> 7, k = j & 127;
        ws[i] = f2bf(wm2[k*64 + nn]);
    }
}

// ---------------- main fused kernel ----------------
// r11: EVERY LDS write->read dependency is separated by a __syncthreads pair
// (stageW). The former intra-wave smolpos handoff is gone: each lane holds its
// own row's smol coords in registers (px,py,pz).
struct __align__(16) SMem {
    unsigned short wbuf[64*72];     // 9216 B staged weight slice [64 rows][64k + 8 pad]
    float  dist[64*17];             // [s][a], pad 17
    float  invd[64*17];
    unsigned short pairT[64*72];    // bf16 [s][k<=64], stride 72
    unsigned short hidT[64*136];    // bf16 [s][k<=128], stride 136
    float  loc[LD];
    float  posall3[ATOT*3];
    float  pl[33];
    float  rot[9];
    float  ca3[3];
    float  wtypef[7*PD];
    float  basev[PD];
    float  gatevv[PD];
    float  lnsc[PD], lnof[PD];
    float  b1v[HD], b2v[PD];
    int    typef[SS];
    float  maskf[SS];
    float  red[4*PD];
    float  fin[PD];
    float  cnt;
};

// Branchless dir-fragment element; own-row coords come in as registers.
__device__ __forceinline__ unsigned short dirbf(const SMem& sm, float px, float py, float pz,
                                                int sl, int k){
    int kc = (k < 48) ? k : 47;
    int a = (kc * 21846) >> 16;     // kc/3
    int c = kc - 3*a;
    float pc = (c == 0) ? px : ((c == 1) ? py : pz);
    float e = (pc - sm.posall3[a*3+c]) * sm.invd[sl*17+a];
    return (k < 48) ? f2bf(e) : (unsigned short)0;
}

// stage a [64 rows][64 k] slice from global (row stride `stride` ushorts)
// into wbuf (row stride 72). Barrier-bracketed: leading barrier closes all
// prior wbuf reads AND drains all waves' prior LDS writes (s_waitcnt before
// s_barrier); trailing barrier publishes the new slice.
__device__ __forceinline__ void stageW(const unsigned short* __restrict__ src, int stride,
                                       unsigned short* dst, int tid){
    __syncthreads();
    int r = tid >> 3, s = (tid & 7) * 8;
    *(u32x4*)&dst[r*72 + s]      = *(const u32x4*)&src[r*stride + s];
    *(u32x4*)&dst[(r+32)*72 + s] = *(const u32x4*)&src[(r+32)*stride + s];
    __syncthreads();
}

__global__ __launch_bounds__(256, 3)
void smol_fused(const float* __restrict__ g_local,
                const float* __restrict__ g_pos,
                const int*   __restrict__ g_type,
                const float* __restrict__ g_spos,
                const int*   __restrict__ g_mask,
                const float* __restrict__ w_points,
                const float* __restrict__ w_local,
                const float* __restrict__ w_type,
                const float* __restrict__ ln_scale,
                const float* __restrict__ ln_offset,
                const float* __restrict__ b_mlp1,
                const float* __restrict__ b_mlp2,
                const float* __restrict__ w_gate,
                const float* __restrict__ w_out,
                const unsigned short* __restrict__ ws,
                float* __restrict__ g_out)
{
    __shared__ SMem sm;
    const int n    = blockIdx.x;
    const int tid  = threadIdx.x;
    const int wv   = tid >> 6;        // wave 0..3 : owns rows 16wv..16wv+15
    const int lane = tid & 63;
    const int cB   = lane & 15;       // A-row / B-col selector
    const int g    = lane >> 4;       // k-subgroup 0..3
    const int m0   = wv * 16;
    const int sl   = m0 + cB;         // this lane's A row (chunk-local s)

    const unsigned short* wsD   = ws;
    const unsigned short* wsDir = ws + 16384;
    const unsigned short* wsM1  = ws + 20480;
    const unsigned short* wsM2  = ws + 28672;

    // ---------- stage per-n data + small weights ----------
    sm.loc[tid] = g_local[n*LD + tid];
    sm.wtypef[tid] = w_type[tid];
    if (tid < 7*PD - 256) sm.wtypef[256 + tid] = w_type[256 + tid];
    if (tid < PD){ sm.lnsc[tid] = ln_scale[tid]; sm.lnof[tid] = ln_offset[tid]; sm.b2v[tid] = b_mlp2[tid]; }
    if (tid < HD) sm.b1v[tid] = b_mlp1[tid];
    if (tid < SS){ sm.typef[tid] = g_type[n*SS + tid];
                   sm.maskf[tid] = (g_mask[n*SS + tid] != 0) ? 1.0f : 0.0f; }
    if (tid >= 128 && tid < 128 + A0C*3) sm.posall3[tid-128] = g_pos[n*A0C*3 + (tid-128)];
    __syncthreads();

    // ---------- per-n precompute ----------
    if (tid < 33){
        float a = 0.f;
        for (int i = 0; i < LD; ++i) a += sm.loc[i] * w_points[i*33 + tid];
        sm.pl[tid] = a;
    } else if (tid >= 64 && tid < 128){
        int p = tid - 64; float a = 0.f;
        for (int i = 0; i < LD; ++i) a += sm.loc[i] * w_local[i*PD + p];
        sm.basev[p] = a;
    } else if (tid >= 128 && tid < 192){
        int p = tid - 128; float a = 0.f;
        for (int i = 0; i < LD; ++i) a += sm.loc[i] * w_gate[i*PD + p];
        sm.gatevv[p] = gelu_f(a);
    } else if (tid == 255){
        float nx=sm.posall3[0], ny=sm.posall3[1], nz=sm.posall3[2];
        float cax=sm.posall3[3], cay=sm.posall3[4], caz=sm.posall3[5];
        float cx=sm.posall3[6], cy=sm.posall3[7], cz=sm.posall3[8];
        float v1x=cx-cax, v1y=cy-cay, v1z=cz-caz;
        float r = 1.0f/sqrtf(v1x*v1x + v1y*v1y + v1z*v1z + 1e-6f);
        float e1x=v1x*r, e1y=v1y*r, e1z=v1z*r;
        float v2x=nx-cax, v2y=ny-cay, v2z=nz-caz;
        float dp = e1x*v2x + e1y*v2y + e1z*v2z;
        float u2x=v2x-e1x*dp, u2y=v2y-e1y*dp, u2z=v2z-e1z*dp;
        r = 1.0f/sqrtf(u2x*u2x + u2y*u2y + u2z*u2z + 1e-6f);
        float e2x=u2x*r, e2y=u2y*r, e2z=u2z*r;
        float e3x=e1y*e2z-e1z*e2y, e3y=e1z*e2x-e1x*e2z, e3z=e1x*e2y-e1y*e2x;
        sm.rot[0]=e1x; sm.rot[1]=e2x; sm.rot[2]=e3x;
        sm.rot[3]=e1y; sm.rot[4]=e2y; sm.rot[5]=e3y;
        sm.rot[6]=e1z; sm.rot[7]=e2z; sm.rot[8]=e3z;
        sm.ca3[0]=cax; sm.ca3[1]=cay; sm.ca3[2]=caz;
    } else if (tid == 254){
        float c = 0.f;
        for (int s = 0; s < SS; ++s) c += sm.maskf[s];
        sm.cnt = c;
    }
    __syncthreads();
    if (tid < 33){
        int k = tid / 3, i2 = tid - k*3;
        sm.posall3[(A0C + k)*3 + i2] =
            sm.rot[i2*3+0]*sm.pl[k*3+0] + sm.rot[i2*3+1]*sm.pl[k*3+1] +
            sm.rot[i2*3+2]*sm.pl[k*3+2] + sm.ca3[i2];
    }
    __syncthreads();   // posall3 visible to all waves

    float pooled0 = 0.f, pooled1 = 0.f, pooled2 = 0.f, pooled3 = 0.f;

    for (int ch = 0; ch < 2; ++ch){
        const int sbase = ch * 64;

        // own-row smol coords in REGISTERS (no LDS handoff)
        const float px = g_spos[(n*SS + sbase + sl)*3 + 0];
        const float py = g_spos[(n*SS + sbase + sl)*3 + 1];
        const float pz = g_spos[(n*SS + sbase + sl)*3 + 2];

        // dist + invd for this wave's 16 rows (lane: row sl, atoms g*4..+4);
        // cross-lane reads happen only AFTER the next stageW barrier.
        #pragma unroll
        for (int aa = 0; aa < 4; ++aa){
            int a = g*4 + aa;
            float rx = px - sm.posall3[a*3+0];
            float ry = py - sm.posall3[a*3+1];
            float rz = pz - sm.posall3[a*3+2];
            float d  = sqrtf(rx*rx + ry*ry + rz*rz + 1e-6f);
            sm.dist[sl*17 + a] = d;
            sm.invd[sl*17 + a] = 1.0f / d;
        }

        // ---- pair GEMM: dist-RBF (K=256), B staged in 4 k-slices of 64 ----
        f32x4 accP0 = {0.f,0.f,0.f,0.f}, accP1 = accP0, accP2 = accP0, accP3 = accP0;

        for (int h = 0; h < 4; ++h){
            stageW(wsD + h*64, 256, sm.wbuf, tid);
            #pragma unroll
            for (int kkl = 0; kkl < 2; ++kkl){
                const int kk = h*2 + kkl;
                float d  = sm.dist[sl*17 + 2*kk + (g>>1)];
                float dd = d * 1.33333333f;
                float b0f = (float)((g&1) * 8);
                float z0 = dd - 1.06666667f*(b0f + 0.f);
                float z1 = dd - 1.06666667f*(b0f + 1.f);
                float z2 = dd - 1.06666667f*(b0f + 2.f);
                float z3 = dd - 1.06666667f*(b0f + 3.f);
                float z4 = dd - 1.06666667f*(b0f + 4.f);
                float z5 = dd - 1.06666667f*(b0f + 5.f);
                float z6 = dd - 1.06666667f*(b0f + 6.f);
                float z7 = dd - 1.06666667f*(b0f + 7.f);
                bf16x8 av;
                av[0] = (short)f2bf(__expf(-z0*z0));
                av[1] = (short)f2bf(__expf(-z1*z1));
                av[2] = (short)f2bf(__expf(-z2*z2));
                av[3] = (short)f2bf(__expf(-z3*z3));
                av[4] = (short)f2bf(__expf(-z4*z4));
                av[5] = (short)f2bf(__expf(-z5*z5));
                av[6] = (short)f2bf(__expf(-z6*z6));
                av[7] = (short)f2bf(__expf(-z7*z7));

                const unsigned short* bb = &sm.wbuf[cB*72 + kkl*32 + g*8];
                accP0 = MFMA(av, *(const bf16x8*)(bb +  0*72), accP0);
                accP1 = MFMA(av, *(const bf16x8*)(bb + 16*72), accP1);
                accP2 = MFMA(av, *(const bf16x8*)(bb + 32*72), accP2);
                accP3 = MFMA(av, *(const bf16x8*)(bb + 48*72), accP3);
            }
        }

        // ---- + directions @ w_dir (K=48 pad 64), one staged slice ----
        stageW(wsDir, 64, sm.wbuf, tid);   // barrier also publishes all invd writes
        #pragma unroll
        for (int kk = 0; kk < 2; ++kk){
            int k0 = kk*32 + g*8;
            bf16x8 av;
            av[0] = (short)dirbf(sm, px, py, pz, sl, k0+0);
            av[1] = (short)dirbf(sm, px, py, pz, sl, k0+1);
            av[2] = (short)dirbf(sm, px, py, pz, sl, k0+2);
            av[3] = (short)dirbf(sm, px, py, pz, sl, k0+3);
            av[4] = (short)dirbf(sm, px, py, pz, sl, k0+4);
            av[5] = (short)dirbf(sm, px, py, pz, sl, k0+5);
            av[6] = (short)dirbf(sm, px, py, pz, sl, k0+6);
            av[7] = (short)dirbf(sm, px, py, pz, sl, k0+7);
            const unsigned short* bb = &sm.wbuf[cB*72 + k0];
            accP0 = MFMA(av, *(const bf16x8*)(bb +  0*72), accP0);
            accP1 = MFMA(av, *(const bf16x8*)(bb + 16*72), accP1);
            accP2 = MFMA(av, *(const bf16x8*)(bb + 32*72), accP2);
            accP3 = MFMA(av, *(const bf16x8*)(bb + 48*72), accP3);
        }

        // ---- epilogue: + base + wtype, LayerNorm, b16 stores to pairT ----
        #pragma unroll
        for (int r = 0; r < 4; ++r){
            int slr = m0 + g*4 + r;
            int ty  = sm.typef[sbase + slr];
            float v0 = accP0[r] + sm.basev[cB +  0] + sm.wtypef[ty*PD + cB +  0];
            float v1 = accP1[r] + sm.basev[cB + 16] + sm.wtypef[ty*PD + cB + 16];
            float v2 = accP2[r] + sm.basev[cB + 32] + sm.wtypef[ty*PD + cB + 32];
            float v3 = accP3[r] + sm.basev[cB + 48] + sm.wtypef[ty*PD + cB + 48];
            float ssum = v0+v1+v2+v3;
            ssum += __shfl_xor(ssum,1); ssum += __shfl_xor(ssum,2);
            ssum += __shfl_xor(ssum,4); ssum += __shfl_xor(ssum,8);
            float mu = ssum * (1.0f/64.0f);
            float d0=v0-mu, d1=v1-mu, d2=v2-mu, d3=v3-mu;
            float sq = d0*d0+d1*d1+d2*d2+d3*d3;
            sq += __shfl_xor(sq,1); sq += __shfl_xor(sq,2);
            sq += __shfl_xor(sq,4); sq += __shfl_xor(sq,8);
            float inv = 1.0f / sqrtf(sq*(1.0f/64.0f) + 1e-5f);
            unsigned short* pr = &sm.pairT[slr*72];
            pr[cB +  0] = f2bf(d0*inv*sm.lnsc[cB +  0] + sm.lnof[cB +  0]);
            pr[cB + 16] = f2bf(d1*inv*sm.lnsc[cB + 16] + sm.lnof[cB + 16]);
            pr[cB + 32] = f2bf(d2*inv*sm.lnsc[cB + 32] + sm.lnof[cB + 32]);
            pr[cB + 48] = f2bf(d3*inv*sm.lnsc[cB + 48] + sm.lnof[cB + 48]);
        }

        // ---- MLP1 (K=64, N=128), B staged in 2 n-slices; stageW barrier
        //      publishes the pairT writes above before any read ----
        f32x4 accH0 = {0.f,0.f,0.f,0.f}, accH1 = accH0, accH2 = accH0, accH3 = accH0,
              accH4 = accH0, accH5 = accH0, accH6 = accH0, accH7 = accH0;
        {
            stageW(wsM1, 64, sm.wbuf, tid);             // n rows 0..63
            #pragma unroll
            for (int kk = 0; kk < 2; ++kk){
                bf16x8 a1 = *(const bf16x8*)&sm.pairT[(m0+cB)*72 + kk*32 + g*8];
                const unsigned short* bb = &sm.wbuf[cB*72 + kk*32 + g*8];
                accH0 = MFMA(a1, *(const bf16x8*)(bb + 0*16*72), accH0);
                accH1 = MFMA(a1, *(const bf16x8*)(bb + 1*16*72), accH1);
                accH2 = MFMA(a1, *(const bf16x8*)(bb + 2*16*72), accH2);
                accH3 = MFMA(a1, *(const bf16x8*)(bb + 3*16*72), accH3);
            }
            stageW(wsM1 + 64*64, 64, sm.wbuf, tid);     // n rows 64..127
            #pragma unroll
            for (int kk = 0; kk < 2; ++kk){
                bf16x8 a1 = *(const bf16x8*)&sm.pairT[(m0+cB)*72 + kk*32 + g*8];
                const unsigned short* bb = &sm.wbuf[cB*72 + kk*32 + g*8];
                accH4 = MFMA(a1, *(const bf16x8*)(bb + 0*16*72), accH4);
                accH5 = MFMA(a1, *(const bf16x8*)(bb + 1*16*72), accH5);
                accH6 = MFMA(a1, *(const bf16x8*)(bb + 2*16*72), accH6);
                accH7 = MFMA(a1, *(const bf16x8*)(bb + 3*16*72), accH7);
            }
        }
        // gelu + b16 stores to hidT
        #pragma unroll
        for (int r = 0; r < 4; ++r){
            int slr = m0 + g*4 + r;
            unsigned short* hr = &sm.hidT[slr*136];
            hr[cB + 0*16] = f2bf(gelu_f(accH0[r] + sm.b1v[cB + 0*16]));
            hr[cB + 1*16] = f2bf(gelu_f(accH1[r] + sm.b1v[cB + 1*16]));
            hr[cB + 2*16] = f2bf(gelu_f(accH2[r] + sm.b1v[cB + 2*16]));
            hr[cB + 3*16] = f2bf(gelu_f(accH3[r] + sm.b1v[cB + 3*16]));
            hr[cB + 4*16] = f2bf(gelu_f(accH4[r] + sm.b1v[cB + 4*16]));
            hr[cB + 5*16] = f2bf(gelu_f(accH5[r] + sm.b1v[cB + 5*16]));
            hr[cB + 6*16] = f2bf(gelu_f(accH6[r] + sm.b1v[cB + 6*16]));
            hr[cB + 7*16] = f2bf(gelu_f(accH7[r] + sm.b1v[cB + 7*16]));
        }

        // ---- MLP2 (K=128, N=64), B staged in 2 k-slices; stageW barrier
        //      publishes the hidT writes above before any read ----
        f32x4 accO0 = {0.f,0.f,0.f,0.f}, accO1 = accO0, accO2 = accO0, accO3 = accO0;
        for (int q = 0; q < 2; ++q){
            stageW(wsM2 + q*64, 128, sm.wbuf, tid);
            #pragma unroll
            for (int kkl = 0; kkl < 2; ++kkl){
                const int kk = q*2 + kkl;
                bf16x8 a2 = *(const bf16x8*)&sm.hidT[(m0+cB)*136 + kk*32 + g*8];
                const unsigned short* bb = &sm.wbuf[cB*72 + kkl*32 + g*8];
                accO0 = MFMA(a2, *(const bf16x8*)(bb + 0*16*72), accO0);
                accO1 = MFMA(a2, *(const bf16x8*)(bb + 1*16*72), accO1);
                accO2 = MFMA(a2, *(const bf16x8*)(bb + 2*16*72), accO2);
                accO3 = MFMA(a2, *(const bf16x8*)(bb + 3*16*72), accO3);
            }
        }
        #pragma unroll
        for (int r = 0; r < 4; ++r){
            float m = sm.maskf[sbase + m0 + g*4 + r];
            pooled0 += m * accO0[r];
            pooled1 += m * accO1[r];
            pooled2 += m * accO2[r];
            pooled3 += m * accO3[r];
        }
    } // chunk loop

    // ---- reduce pooled: across g-groups (same col), then across waves ----
    pooled0 += __shfl_xor(pooled0,16); pooled0 += __shfl_xor(pooled0,32);
    pooled1 += __shfl_xor(pooled1,16); pooled1 += __shfl_xor(pooled1,32);
    pooled2 += __shfl_xor(pooled2,16); pooled2 += __shfl_xor(pooled2,32);
    pooled3 += __shfl_xor(pooled3,16); pooled3 += __shfl_xor(pooled3,32);
    if (g == 0){
        sm.red[wv*PD + cB +  0] = pooled0;
        sm.red[wv*PD + cB + 16] = pooled1;
        sm.red[wv*PD + cB + 32] = pooled2;
        sm.red[wv*PD + cB + 48] = pooled3;
    }
    __syncthreads();
    if (tid < PD){
        float v = sm.red[tid] + sm.red[PD + tid] + sm.red[2*PD + tid] + sm.red[3*PD + tid];
        float mc = fmaxf(sm.cnt, 1.0f);
        v = (v + sm.cnt * sm.b2v[tid]) / mc;        // adds b2 exactly like ref (0 if cnt==0)
        sm.fin[tid] = sm.gatevv[tid] * v;
    }
    __syncthreads();
    {
        float a = 0.f;
        #pragma unroll 4
        for (int p = 0; p < PD; ++p) a += sm.fin[p] * w_out[p*LD + tid];
        g_out[n*LD + tid] = a;
    }
}

extern "C" void kernel_launch(void* const* d_in, const int* in_sizes, int n_in,
                              void* d_out, int out_size, void* d_ws, size_t ws_size,
                              hipStream_t stream)
{
    (void)in_sizes; (void)n_in; (void)out_size; (void)ws_size;
    const float* g_local   = (const float*)d_in[0];
    const float* g_pos     = (const float*)d_in[1];
    const int*   g_type    = (const int*)  d_in[2];
    const float* g_spos    = (const float*)d_in[3];
    const int*   g_mask    = (const int*)  d_in[4];
    const float* w_points  = (const float*)d_in[5];
    const float* w_type    = (const float*)d_in[6];
    const float* w_local   = (const float*)d_in[7];
    const float* w_dir     = (const float*)d_in[8];
    const float* w_dist    = (const float*)d_in[9];
    const float* ln_scale  = (const float*)d_in[10];
    const float* ln_offset = (const float*)d_in[11];
    const float* w_mlp1    = (const float*)d_in[12];
    const float* b_mlp1    = (const float*)d_in[13];
    const float* w_mlp2    = (const float*)d_in[14];
    const float* b_mlp2    = (const float*)d_in[15];
    const float* w_gate    = (const float*)d_in[16];
    const float* w_out     = (const float*)d_in[17];

    unsigned short* ws = (unsigned short*)d_ws;   // 73728 B

    smol_prep<<<dim3(144), dim3(256), 0, stream>>>(w_dist, w_dir, w_mlp1, w_mlp2, ws);

    smol_fused<<<dim3(NRES), dim3(256), 0, stream>>>(
        g_local, g_pos, g_type, g_spos, g_mask,
        w_points, w_local, w_type, ln_scale, ln_offset,
        b_mlp1, b_mlp2, w_gate, w_out, ws, (float*)d_out);
}

// Round 13
// 207.854 us; speedup vs baseline: 2.4252x; 1.2119x over previous
//
#include <hip/hip_runtime.h>
#include <math.h>

#define NRES 4096
#define SS   128
#define A0C  5
#define ATOT 16
#define LD   256
#define PD   64
#define HD   128

typedef __attribute__((ext_vector_type(8))) short bf16x8;
typedef __attribute__((ext_vector_type(4))) float f32x4;
typedef __attribute__((ext_vector_type(4))) unsigned int u32x4;

__device__ __forceinline__ unsigned short f2bf(float x){
    unsigned int u = __builtin_bit_cast(unsigned int, x);
    unsigned int r = u + 0x7FFFu + ((u >> 16) & 1u);   // RNE to bf16
    return (unsigned short)(r >> 16);
}
__device__ __forceinline__ float gelu_f(float x){
    // x/(1+e^{-2t}), 2t = 1.59576912*(x + 0.044715 x^3)  == tanh-gelu exactly
    return x / (1.0f + __expf(-1.59576912f * x * (1.0f + 0.044715f * x * x)));
}
__device__ __forceinline__ f32x4 MFMA(bf16x8 a, bf16x8 b, f32x4 c){
    return __builtin_amdgcn_mfma_f32_16x16x32_bf16(a, b, c, 0, 0, 0);
}

// ---------------- prep: transpose+convert weights to bf16 in d_ws ----------------
// layout (ushort elements)  [identical to r5..r11 — 73728 B total]:
//   [0)      wsD   [64 n][256 k]   (w_dist^T)
//   [16384)  wsDir [64 n][64 k]    (w_dir^T, k>=48 zero)
//   [20480)  wsM1  [128 n][64 k]   (w_mlp1^T)
//   [28672)  wsM2  [64 n][128 k]   (w_mlp2^T)
__global__ void smol_prep(const float* __restrict__ wdist, const float* __restrict__ wdir,
                          const float* __restrict__ wm1,  const float* __restrict__ wm2,
                          unsigned short* __restrict__ ws)
{
    int i = blockIdx.x * 256 + threadIdx.x;
    if (i < 16384){
        int nn = i >> 8, k = i & 255;
        ws[i] = f2bf(wdist[k*64 + nn]);
    } else if (i < 20480){
        int j = i - 16384; int nn = j >> 6, k = j & 63;
        ws[i] = (k < 48) ? f2bf(wdir[k*64 + nn]) : (unsigned short)0;
    } else if (i < 28672){
        int j = i - 20480; int nn = j >> 6, k = j & 63;
        ws[i] = f2bf(wm1[k*128 + nn]);
    } else if (i < 36864){
        int j = i - 28672; int nn = j >> 7, k = j & 127;
        ws[i] = f2bf(wm2[k*64 + nn]);
    }
}

// ---------------- main fused kernel ----------------
// r13 = r12's single-pass structure + r11's KNOWN-GOOD value plumbing
// (manual-RNE f2bf element inserts, exact 1/d). Bisects r12's failure:
// structure vs cvt_pk asm.
struct __align__(16) SMem {
    unsigned short wbuf[64*72];     // 9216 B staged weight slice
    float  dist[128*17];            // [s][a], pad 17
    unsigned short pairT[128*72];   // bf16 [s][k<=64], stride 72
    unsigned short hidT[128*136];   // bf16 [s][k<=128], stride 136
    float  loc[LD];
    float  posall3[ATOT*3];
    float  pl[33];
    float  rot[9];
    float  ca3[3];
    float  wtypef[7*PD];
    float  basev[PD];
    float  gatevv[PD];
    float  lnsc[PD], lnof[PD];
    float  b1v[HD], b2v[PD];
    int    typef[SS];
    float  maskf[SS];
    float  red[4*PD];
    float  fin[PD];
    float  cnt;
};

// dir element: own-row coords in registers; exact IEEE divide (r11 semantics)
__device__ __forceinline__ float dirv2(const SMem& sm, float px, float py, float pz,
                                       int sl, int k){
    int kc = (k < 48) ? k : 47;
    int a = (kc * 21846) >> 16;     // kc/3
    int c = kc - 3*a;
    float pc = (c == 0) ? px : ((c == 1) ? py : pz);
    float e = (pc - sm.posall3[a*3+c]) / sm.dist[sl*17 + a];
    return (k < 48) ? e : 0.0f;
}

// stage a [64 rows][64 k] slice from global (row stride `stride` ushorts)
// into wbuf (row stride 72). Leading barrier closes prior wbuf reads AND
// publishes all waves' prior LDS writes; trailing barrier publishes the slice.
__device__ __forceinline__ void stageW(const unsigned short* __restrict__ src, int stride,
                                       unsigned short* dst, int tid){
    __syncthreads();
    int r = tid >> 3, s = (tid & 7) * 8;
    *(u32x4*)&dst[r*72 + s]      = *(const u32x4*)&src[r*stride + s];
    *(u32x4*)&dst[(r+32)*72 + s] = *(const u32x4*)&src[(r+32)*stride + s];
    __syncthreads();
}

// RBF A-fragment for row sl, k-block kk (8 bins of atom 2kk+(g>>1)), f2bf inserts
#define RBF_FRAG(av, sl) do {                                               \
    float d_  = sm.dist[(sl)*17 + 2*kk + (g>>1)];                           \
    float dd_ = d_ * 1.33333333f;                                           \
    float z0_ = dd_ - 1.06666667f*(b0f + 0.f);                              \
    float z1_ = dd_ - 1.06666667f*(b0f + 1.f);                              \
    float z2_ = dd_ - 1.06666667f*(b0f + 2.f);                              \
    float z3_ = dd_ - 1.06666667f*(b0f + 3.f);                              \
    float z4_ = dd_ - 1.06666667f*(b0f + 4.f);                              \
    float z5_ = dd_ - 1.06666667f*(b0f + 5.f);                              \
    float z6_ = dd_ - 1.06666667f*(b0f + 6.f);                              \
    float z7_ = dd_ - 1.06666667f*(b0f + 7.f);                              \
    av[0] = (short)f2bf(__expf(-z0_*z0_));                                  \
    av[1] = (short)f2bf(__expf(-z1_*z1_));                                  \
    av[2] = (short)f2bf(__expf(-z2_*z2_));                                  \
    av[3] = (short)f2bf(__expf(-z3_*z3_));                                  \
    av[4] = (short)f2bf(__expf(-z4_*z4_));                                  \
    av[5] = (short)f2bf(__expf(-z5_*z5_));                                  \
    av[6] = (short)f2bf(__expf(-z6_*z6_));                                  \
    av[7] = (short)f2bf(__expf(-z7_*z7_));                                  \
} while(0)

__global__ __launch_bounds__(256, 2)
void smol_fused(const float* __restrict__ g_local,
                const float* __restrict__ g_pos,
                const int*   __restrict__ g_type,
                const float* __restrict__ g_spos,
                const int*   __restrict__ g_mask,
                const float* __restrict__ w_points,
                const float* __restrict__ w_local,
                const float* __restrict__ w_type,
                const float* __restrict__ ln_scale,
                const float* __restrict__ ln_offset,
                const float* __restrict__ b_mlp1,
                const float* __restrict__ b_mlp2,
                const float* __restrict__ w_gate,
                const float* __restrict__ w_out,
                const unsigned short* __restrict__ ws,
                float* __restrict__ g_out)
{
    __shared__ SMem sm;
    const int n    = blockIdx.x;
    const int tid  = threadIdx.x;
    const int wv   = tid >> 6;        // wave 0..3 : owns rows 32wv..32wv+31
    const int lane = tid & 63;
    const int cB   = lane & 15;       // A-row / B-col selector
    const int g    = lane >> 4;       // k-subgroup 0..3
    const int sl0  = 32*wv + cB;      // tile-0 A row (s index)
    const int sl1  = sl0 + 16;        // tile-1 A row

    const unsigned short* wsD   = ws;
    const unsigned short* wsDir = ws + 16384;
    const unsigned short* wsM1  = ws + 20480;
    const unsigned short* wsM2  = ws + 28672;

    // ---------- stage per-n data + small weights ----------
    sm.loc[tid] = g_local[n*LD + tid];
    sm.wtypef[tid] = w_type[tid];
    if (tid < 7*PD - 256) sm.wtypef[256 + tid] = w_type[256 + tid];
    if (tid < PD){ sm.lnsc[tid] = ln_scale[tid]; sm.lnof[tid] = ln_offset[tid]; sm.b2v[tid] = b_mlp2[tid]; }
    if (tid < HD) sm.b1v[tid] = b_mlp1[tid];
    if (tid < SS){ sm.typef[tid] = g_type[n*SS + tid];
                   sm.maskf[tid] = (g_mask[n*SS + tid] != 0) ? 1.0f : 0.0f; }
    if (tid >= 128 && tid < 128 + A0C*3) sm.posall3[tid-128] = g_pos[n*A0C*3 + (tid-128)];
    __syncthreads();

    // ---------- per-n precompute ----------
    if (tid < 33){
        float a = 0.f;
        for (int i = 0; i < LD; ++i) a += sm.loc[i] * w_points[i*33 + tid];
        sm.pl[tid] = a;
    } else if (tid >= 64 && tid < 128){
        int p = tid - 64; float a = 0.f;
        for (int i = 0; i < LD; ++i) a += sm.loc[i] * w_local[i*PD + p];
        sm.basev[p] = a;
    } else if (tid >= 128 && tid < 192){
        int p = tid - 128; float a = 0.f;
        for (int i = 0; i < LD; ++i) a += sm.loc[i] * w_gate[i*PD + p];
        sm.gatevv[p] = gelu_f(a);
    } else if (tid == 255){
        float nx=sm.posall3[0], ny=sm.posall3[1], nz=sm.posall3[2];
        float cax=sm.posall3[3], cay=sm.posall3[4], caz=sm.posall3[5];
        float cx=sm.posall3[6], cy=sm.posall3[7], cz=sm.posall3[8];
        float v1x=cx-cax, v1y=cy-cay, v1z=cz-caz;
        float r = 1.0f/sqrtf(v1x*v1x + v1y*v1y + v1z*v1z + 1e-6f);
        float e1x=v1x*r, e1y=v1y*r, e1z=v1z*r;
        float v2x=nx-cax, v2y=ny-cay, v2z=nz-caz;
        float dp = e1x*v2x + e1y*v2y + e1z*v2z;
        float u2x=v2x-e1x*dp, u2y=v2y-e1y*dp, u2z=v2z-e1z*dp;
        r = 1.0f/sqrtf(u2x*u2x + u2y*u2y + u2z*u2z + 1e-6f);
        float e2x=u2x*r, e2y=u2y*r, e2z=u2z*r;
        float e3x=e1y*e2z-e1z*e2y, e3y=e1z*e2x-e1x*e2z, e3z=e1x*e2y-e1y*e2x;
        sm.rot[0]=e1x; sm.rot[1]=e2x; sm.rot[2]=e3x;
        sm.rot[3]=e1y; sm.rot[4]=e2y; sm.rot[5]=e3y;
        sm.rot[6]=e1z; sm.rot[7]=e2z; sm.rot[8]=e3z;
        sm.ca3[0]=cax; sm.ca3[1]=cay; sm.ca3[2]=caz;
    } else if (tid == 254){
        float c = 0.f;
        for (int s = 0; s < SS; ++s) c += sm.maskf[s];
        sm.cnt = c;
    }
    __syncthreads();
    if (tid < 33){
        int k = tid / 3, i2 = tid - k*3;
        sm.posall3[(A0C + k)*3 + i2] =
            sm.rot[i2*3+0]*sm.pl[k*3+0] + sm.rot[i2*3+1]*sm.pl[k*3+1] +
            sm.rot[i2*3+2]*sm.pl[k*3+2] + sm.ca3[i2];
    }
    __syncthreads();   // posall3 visible to all waves

    // own-row smol coords in REGISTERS (no LDS handoff)
    const float px0 = g_spos[(n*SS + sl0)*3 + 0];
    const float py0 = g_spos[(n*SS + sl0)*3 + 1];
    const float pz0 = g_spos[(n*SS + sl0)*3 + 2];
    const float px1 = g_spos[(n*SS + sl1)*3 + 0];
    const float py1 = g_spos[(n*SS + sl1)*3 + 1];
    const float pz1 = g_spos[(n*SS + sl1)*3 + 2];

    // dist for this wave's 32 rows (lane: rows sl0/sl1, atoms g*4..+4);
    // cross-lane reads happen only AFTER the next stageW barrier.
    #pragma unroll
    for (int aa = 0; aa < 4; ++aa){
        int a = g*4 + aa;
        float ax = sm.posall3[a*3+0], ay = sm.posall3[a*3+1], az = sm.posall3[a*3+2];
        float rx0 = px0-ax, ry0 = py0-ay, rz0 = pz0-az;
        sm.dist[sl0*17 + a] = sqrtf(rx0*rx0 + ry0*ry0 + rz0*rz0 + 1e-6f);
        float rx1 = px1-ax, ry1 = py1-ay, rz1 = pz1-az;
        sm.dist[sl1*17 + a] = sqrtf(rx1*rx1 + ry1*ry1 + rz1*rz1 + 1e-6f);
    }

    const float b0f = (float)((g&1) * 8);

    // ---- pair GEMM: dist-RBF (K=256), B staged once in 4 k-slices ----
    f32x4 accP0 = {0.f,0.f,0.f,0.f}, accP1 = accP0, accP2 = accP0, accP3 = accP0;  // tile 0
    f32x4 accQ0 = accP0, accQ1 = accP0, accQ2 = accP0, accQ3 = accP0;              // tile 1

    for (int h = 0; h < 4; ++h){
        stageW(wsD + h*64, 256, sm.wbuf, tid);
        #pragma unroll
        for (int kkl = 0; kkl < 2; ++kkl){
            const int kk = h*2 + kkl;
            bf16x8 av0, av1;
            RBF_FRAG(av0, sl0);
            RBF_FRAG(av1, sl1);
            const unsigned short* bb = &sm.wbuf[cB*72 + kkl*32 + g*8];
            bf16x8 B0 = *(const bf16x8*)(bb +  0*72);
            bf16x8 B1 = *(const bf16x8*)(bb + 16*72);
            bf16x8 B2 = *(const bf16x8*)(bb + 32*72);
            bf16x8 B3 = *(const bf16x8*)(bb + 48*72);
            accP0 = MFMA(av0, B0, accP0);  accQ0 = MFMA(av1, B0, accQ0);
            accP1 = MFMA(av0, B1, accP1);  accQ1 = MFMA(av1, B1, accQ1);
            accP2 = MFMA(av0, B2, accP2);  accQ2 = MFMA(av1, B2, accQ2);
            accP3 = MFMA(av0, B3, accP3);  accQ3 = MFMA(av1, B3, accQ3);
        }
    }

    // ---- + directions @ w_dir (K=48 pad 64), one staged slice ----
    stageW(wsDir, 64, sm.wbuf, tid);
    #pragma unroll
    for (int kk = 0; kk < 2; ++kk){
        int k0 = kk*32 + g*8;
        bf16x8 av0, av1;
        av0[0] = (short)f2bf(dirv2(sm,px0,py0,pz0,sl0,k0+0));
        av0[1] = (short)f2bf(dirv2(sm,px0,py0,pz0,sl0,k0+1));
        av0[2] = (short)f2bf(dirv2(sm,px0,py0,pz0,sl0,k0+2));
        av0[3] = (short)f2bf(dirv2(sm,px0,py0,pz0,sl0,k0+3));
        av0[4] = (short)f2bf(dirv2(sm,px0,py0,pz0,sl0,k0+4));
        av0[5] = (short)f2bf(dirv2(sm,px0,py0,pz0,sl0,k0+5));
        av0[6] = (short)f2bf(dirv2(sm,px0,py0,pz0,sl0,k0+6));
        av0[7] = (short)f2bf(dirv2(sm,px0,py0,pz0,sl0,k0+7));
        av1[0] = (short)f2bf(dirv2(sm,px1,py1,pz1,sl1,k0+0));
        av1[1] = (short)f2bf(dirv2(sm,px1,py1,pz1,sl1,k0+1));
        av1[2] = (short)f2bf(dirv2(sm,px1,py1,pz1,sl1,k0+2));
        av1[3] = (short)f2bf(dirv2(sm,px1,py1,pz1,sl1,k0+3));
        av1[4] = (short)f2bf(dirv2(sm,px1,py1,pz1,sl1,k0+4));
        av1[5] = (short)f2bf(dirv2(sm,px1,py1,pz1,sl1,k0+5));
        av1[6] = (short)f2bf(dirv2(sm,px1,py1,pz1,sl1,k0+6));
        av1[7] = (short)f2bf(dirv2(sm,px1,py1,pz1,sl1,k0+7));
        const unsigned short* bb = &sm.wbuf[cB*72 + k0];
        bf16x8 B0 = *(const bf16x8*)(bb +  0*72);
        bf16x8 B1 = *(const bf16x8*)(bb + 16*72);
        bf16x8 B2 = *(const bf16x8*)(bb + 32*72);
        bf16x8 B3 = *(const bf16x8*)(bb + 48*72);
        accP0 = MFMA(av0, B0, accP0);  accQ0 = MFMA(av1, B0, accQ0);
        accP1 = MFMA(av0, B1, accP1);  accQ1 = MFMA(av1, B1, accQ1);
        accP2 = MFMA(av0, B2, accP2);  accQ2 = MFMA(av1, B2, accQ2);
        accP3 = MFMA(av0, B3, accP3);  accQ3 = MFMA(av1, B3, accQ3);
    }

    // ---- epilogue: + base + wtype, LayerNorm, f2bf stores to pairT ----
    #pragma unroll
    for (int t = 0; t < 2; ++t){
        #pragma unroll
        for (int r = 0; r < 4; ++r){
            int slr = 32*wv + 16*t + g*4 + r;
            int ty  = sm.typef[slr];
            float a0 = (t==0 ? accP0[r] : accQ0[r]);
            float a1 = (t==0 ? accP1[r] : accQ1[r]);
            float a2 = (t==0 ? accP2[r] : accQ2[r]);
            float a3 = (t==0 ? accP3[r] : accQ3[r]);
            float v0 = a0 + sm.basev[cB +  0] + sm.wtypef[ty*PD + cB +  0];
            float v1 = a1 + sm.basev[cB + 16] + sm.wtypef[ty*PD + cB + 16];
            float v2 = a2 + sm.basev[cB + 32] + sm.wtypef[ty*PD + cB + 32];
            float v3 = a3 + sm.basev[cB + 48] + sm.wtypef[ty*PD + cB + 48];
            float ssum = v0+v1+v2+v3;
            ssum += __shfl_xor(ssum,1); ssum += __shfl_xor(ssum,2);
            ssum += __shfl_xor(ssum,4); ssum += __shfl_xor(ssum,8);
            float mu = ssum * (1.0f/64.0f);
            float d0=v0-mu, d1=v1-mu, d2=v2-mu, d3=v3-mu;
            float sq = d0*d0+d1*d1+d2*d2+d3*d3;
            sq += __shfl_xor(sq,1); sq += __shfl_xor(sq,2);
            sq += __shfl_xor(sq,4); sq += __shfl_xor(sq,8);
            float inv = 1.0f / sqrtf(sq*(1.0f/64.0f) + 1e-5f);
            unsigned short* pr = &sm.pairT[slr*72];
            pr[cB +  0] = f2bf(d0*inv*sm.lnsc[cB +  0] + sm.lnof[cB +  0]);
            pr[cB + 16] = f2bf(d1*inv*sm.lnsc[cB + 16] + sm.lnof[cB + 16]);
            pr[cB + 32] = f2bf(d2*inv*sm.lnsc[cB + 32] + sm.lnof[cB + 32]);
            pr[cB + 48] = f2bf(d3*inv*sm.lnsc[cB + 48] + sm.lnof[cB + 48]);
        }
    }

    // ---- MLP1 (K=64, N=128), staged in 2 n-slices; leading barrier of each
    //      stageW publishes the pairT writes above before any read ----
    f32x4 accH0 = {0.f,0.f,0.f,0.f}, accH1 = accH0, accH2 = accH0, accH3 = accH0,
          accH4 = accH0, accH5 = accH0, accH6 = accH0, accH7 = accH0;   // tile 0
    f32x4 accI0 = accH0, accI1 = accH0, accI2 = accH0, accI3 = accH0,
          accI4 = accH0, accI5 = accH0, accI6 = accH0, accI7 = accH0;   // tile 1
    {
        stageW(wsM1, 64, sm.wbuf, tid);             // n rows 0..63
        #pragma unroll
        for (int kk = 0; kk < 2; ++kk){
            bf16x8 a0 = *(const bf16x8*)&sm.pairT[sl0*72 + kk*32 + g*8];
            bf16x8 a1 = *(const bf16x8*)&sm.pairT[sl1*72 + kk*32 + g*8];
            const unsigned short* bb = &sm.wbuf[cB*72 + kk*32 + g*8];
            bf16x8 B0 = *(const bf16x8*)(bb + 0*16*72);
            bf16x8 B1 = *(const bf16x8*)(bb + 1*16*72);
            bf16x8 B2 = *(const bf16x8*)(bb + 2*16*72);
            bf16x8 B3 = *(const bf16x8*)(bb + 3*16*72);
            accH0 = MFMA(a0, B0, accH0);  accI0 = MFMA(a1, B0, accI0);
            accH1 = MFMA(a0, B1, accH1);  accI1 = MFMA(a1, B1, accI1);
            accH2 = MFMA(a0, B2, accH2);  accI2 = MFMA(a1, B2, accI2);
            accH3 = MFMA(a0, B3, accH3);  accI3 = MFMA(a1, B3, accI3);
        }
        stageW(wsM1 + 64*64, 64, sm.wbuf, tid);     // n rows 64..127
        #pragma unroll
        for (int kk = 0; kk < 2; ++kk){
            bf16x8 a0 = *(const bf16x8*)&sm.pairT[sl0*72 + kk*32 + g*8];
            bf16x8 a1 = *(const bf16x8*)&sm.pairT[sl1*72 + kk*32 + g*8];
            const unsigned short* bb = &sm.wbuf[cB*72 + kk*32 + g*8];
            bf16x8 B0 = *(const bf16x8*)(bb + 0*16*72);
            bf16x8 B1 = *(const bf16x8*)(bb + 1*16*72);
            bf16x8 B2 = *(const bf16x8*)(bb + 2*16*72);
            bf16x8 B3 = *(const bf16x8*)(bb + 3*16*72);
            accH4 = MFMA(a0, B0, accH4);  accI4 = MFMA(a1, B0, accI4);
            accH5 = MFMA(a0, B1, accH5);  accI5 = MFMA(a1, B1, accI5);
            accH6 = MFMA(a0, B2, accH6);  accI6 = MFMA(a1, B2, accI6);
            accH7 = MFMA(a0, B3, accH7);  accI7 = MFMA(a1, B3, accI7);
        }
    }
    // gelu + f2bf stores to hidT
    #pragma unroll
    for (int r = 0; r < 4; ++r){
        int slr0 = 32*wv + g*4 + r;
        unsigned short* hr0 = &sm.hidT[slr0*136];
        hr0[cB + 0*16] = f2bf(gelu_f(accH0[r] + sm.b1v[cB + 0*16]));
        hr0[cB + 1*16] = f2bf(gelu_f(accH1[r] + sm.b1v[cB + 1*16]));
        hr0[cB + 2*16] = f2bf(gelu_f(accH2[r] + sm.b1v[cB + 2*16]));
        hr0[cB + 3*16] = f2bf(gelu_f(accH3[r] + sm.b1v[cB + 3*16]));
        hr0[cB + 4*16] = f2bf(gelu_f(accH4[r] + sm.b1v[cB + 4*16]));
        hr0[cB + 5*16] = f2bf(gelu_f(accH5[r] + sm.b1v[cB + 5*16]));
        hr0[cB + 6*16] = f2bf(gelu_f(accH6[r] + sm.b1v[cB + 6*16]));
        hr0[cB + 7*16] = f2bf(gelu_f(accH7[r] + sm.b1v[cB + 7*16]));
        unsigned short* hr1 = &sm.hidT[(slr0+16)*136];
        hr1[cB + 0*16] = f2bf(gelu_f(accI0[r] + sm.b1v[cB + 0*16]));
        hr1[cB + 1*16] = f2bf(gelu_f(accI1[r] + sm.b1v[cB + 1*16]));
        hr1[cB + 2*16] = f2bf(gelu_f(accI2[r] + sm.b1v[cB + 2*16]));
        hr1[cB + 3*16] = f2bf(gelu_f(accI3[r] + sm.b1v[cB + 3*16]));
        hr1[cB + 4*16] = f2bf(gelu_f(accI4[r] + sm.b1v[cB + 4*16]));
        hr1[cB + 5*16] = f2bf(gelu_f(accI5[r] + sm.b1v[cB + 5*16]));
        hr1[cB + 6*16] = f2bf(gelu_f(accI6[r] + sm.b1v[cB + 6*16]));
        hr1[cB + 7*16] = f2bf(gelu_f(accI7[r] + sm.b1v[cB + 7*16]));
    }

    // ---- MLP2 (K=128, N=64), staged in 2 k-slices; leading barrier of each
    //      stageW publishes the hidT writes above before any read ----
    f32x4 accO0 = {0.f,0.f,0.f,0.f}, accO1 = accO0, accO2 = accO0, accO3 = accO0;  // tile 0
    f32x4 accN0 = accO0, accN1 = accO0, accN2 = accO0, accN3 = accO0;              // tile 1
    for (int q = 0; q < 2; ++q){
        stageW(wsM2 + q*64, 128, sm.wbuf, tid);
        #pragma unroll
        for (int kkl = 0; kkl < 2; ++kkl){
            const int kk = q*2 + kkl;
            bf16x8 a0 = *(const bf16x8*)&sm.hidT[sl0*136 + kk*32 + g*8];
            bf16x8 a1 = *(const bf16x8*)&sm.hidT[sl1*136 + kk*32 + g*8];
            const unsigned short* bb = &sm.wbuf[cB*72 + kkl*32 + g*8];
            bf16x8 B0 = *(const bf16x8*)(bb + 0*16*72);
            bf16x8 B1 = *(const bf16x8*)(bb + 1*16*72);
            bf16x8 B2 = *(const bf16x8*)(bb + 2*16*72);
            bf16x8 B3 = *(const bf16x8*)(bb + 3*16*72);
            accO0 = MFMA(a0, B0, accO0);  accN0 = MFMA(a1, B0, accN0);
            accO1 = MFMA(a0, B1, accO1);  accN1 = MFMA(a1, B1, accN1);
            accO2 = MFMA(a0, B2, accO2);  accN2 = MFMA(a1, B2, accN2);
            accO3 = MFMA(a0, B3, accO3);  accN3 = MFMA(a1, B3, accN3);
        }
    }
    float pooled0 = 0.f, pooled1 = 0.f, pooled2 = 0.f, pooled3 = 0.f;
    #pragma unroll
    for (int r = 0; r < 4; ++r){
        float m0f = sm.maskf[32*wv + g*4 + r];
        float m1f = sm.maskf[32*wv + 16 + g*4 + r];
        pooled0 += m0f * accO0[r] + m1f * accN0[r];
        pooled1 += m0f * accO1[r] + m1f * accN1[r];
        pooled2 += m0f * accO2[r] + m1f * accN2[r];
        pooled3 += m0f * accO3[r] + m1f * accN3[r];
    }

    // ---- reduce pooled: across g-groups (same col), then across waves ----
    pooled0 += __shfl_xor(pooled0,16); pooled0 += __shfl_xor(pooled0,32);
    pooled1 += __shfl_xor(pooled1,16); pooled1 += __shfl_xor(pooled1,32);
    pooled2 += __shfl_xor(pooled2,16); pooled2 += __shfl_xor(pooled2,32);
    pooled3 += __shfl_xor(pooled3,16); pooled3 += __shfl_xor(pooled3,32);
    if (g == 0){
        sm.red[wv*PD + cB +  0] = pooled0;
        sm.red[wv*PD + cB + 16] = pooled1;
        sm.red[wv*PD + cB + 32] = pooled2;
        sm.red[wv*PD + cB + 48] = pooled3;
    }
    __syncthreads();
    if (tid < PD){
        float v = sm.red[tid] + sm.red[PD + tid] + sm.red[2*PD + tid] + sm.red[3*PD + tid];
        float mc = fmaxf(sm.cnt, 1.0f);
        v = (v + sm.cnt * sm.b2v[tid]) / mc;        // adds b2 exactly like ref (0 if cnt==0)
        sm.fin[tid] = sm.gatevv[tid] * v;
    }
    __syncthreads();
    {
        float a = 0.f;
        #pragma unroll 4
        for (int p = 0; p < PD; ++p) a += sm.fin[p] * w_out[p*LD + tid];
        g_out[n*LD + tid] = a;
    }
}

extern "C" void kernel_launch(void* const* d_in, const int* in_sizes, int n_in,
                              void* d_out, int out_size, void* d_ws, size_t ws_size,
                              hipStream_t stream)
{
    (void)in_sizes; (void)n_in; (void)out_size; (void)ws_size;
    const float* g_local   = (const float*)d_in[0];
    const float* g_pos     = (const float*)d_in[1];
    const int*   g_type    = (const int*)  d_in[2];
    const float* g_spos    = (const float*)d_in[3];
    const int*   g_mask    = (const int*)  d_in[4];
    const float* w_points  = (const float*)d_in[5];
    const float* w_type    = (const float*)d_in[6];
    const float* w_local   = (const float*)d_in[7];
    const float* w_dir     = (const float*)d_in[8];
    const float* w_dist    = (const float*)d_in[9];
    const float* ln_scale  = (const float*)d_in[10];
    const float* ln_offset = (const float*)d_in[11];
    const float* w_mlp1    = (const float*)d_in[12];
    const float* b_mlp1    = (const float*)d_in[13];
    const float* w_mlp2    = (const float*)d_in[14];
    const float* b_mlp2    = (const float*)d_in[15];
    const float* w_gate    = (const float*)d_in[16];
    const float* w_out     = (const float*)d_in[17];

    unsigned short* ws = (unsigned short*)d_ws;   // 73728 B

    smol_prep<<<dim3(144), dim3(256), 0, stream>>>(w_dist, w_dir, w_mlp1, w_mlp2, ws);

    smol_fused<<<dim3(NRES), dim3(256), 0, stream>>>(
        g_local, g_pos, g_type, g_spos, g_mask,
        w_points, w_local, w_type, ln_scale, ln_offset,
        b_mlp1, b_mlp2, w_gate, w_out, ws, (float*)d_out);
}